// Round 8
// baseline (41.006 us; speedup 1.0000x reference)
//
#include <hip/hip_runtime.h>
#include <math.h>

#define KNN 8
#define QPB 16          // queries per block
#define SUB 16          // sub-lanes per query
#define BLK 256         // QPB*SUB threads, 4 waves
#define NBMAX 256       // batch-id table capacity

// Kernel A: compact {x,y,z,|c|^2} for every x1 row + lower-bound table for b1.
// s1[b] = first index i with b1[i] >= b  (b1 sorted; unique writer per entry).
__global__ void knn_prep(const float* __restrict__ x1,
                         const int* __restrict__ b1,
                         int N, int ROW,
                         float4* __restrict__ c4,
                         int* __restrict__ s1) {
  int i = blockIdx.x * blockDim.x + threadIdx.x;
  if (i >= N) return;
  const float* p = x1 + (size_t)i * ROW;
  float x = p[0], y = p[1], z = p[2];
  c4[i] = make_float4(x, y, z, x * x + y * y + z * z);
  int bc = b1[i];
  int bp = (i == 0) ? -1 : b1[i - 1];
  for (int b = bp + 1; b <= bc; ++b) s1[b] = i;
  if (i == N - 1) { for (int b = bc + 1; b <= NBMAX + 1; ++b) s1[b] = N; }
}

// Kernel B: zero-setup select+gather. Per thread: 2 table loads -> scan the
// L2-hot compact c4[] (16-way sliced, sorted top-8 in registers) -> exact
// lexicographic (d, idx) shuffle merge fused with the feature gather (each
// round's winner, converged in all 16 lanes, immediately accumulates; lane
// owns dims (lane&15)+{0,16,...,112}). One deterministic partial per block.
__launch_bounds__(BLK, 8)
__global__ void knn_main(const float4* __restrict__ c4,
                         const float* __restrict__ x1,
                         const float* __restrict__ x2,
                         const int* __restrict__ b2,
                         const int* __restrict__ s1,
                         int N, int ROW,
                         float* __restrict__ ws_part) {
  __shared__ float wred[BLK / 64];
  const int tid  = threadIdx.x;
  const int lane = tid & 63;
  const int wv   = tid >> 6;          // 0..3
  const int qi   = tid >> 4;          // query within block (SUB=16)
  const int sub  = tid & (SUB - 1);
  const int dl   = lane & 15;         // owned feature dim base
  const int q    = blockIdx.x * QPB + qi;

  float qx = 0.f, qy = 0.f, qz = 0.f;
  int qs = 0, qe = 0;
  float f2v[KNN];
#pragma unroll
  for (int r = 0; r < KNN; ++r) f2v[r] = 0.f;
  if (q < N) {
    const float* c2 = x2 + (size_t)q * ROW;
    qx = c2[0]; qy = c2[1]; qz = c2[2];
    int mb = b2[q];
    qs = s1[mb]; qe = s1[mb + 1];
    const float* f2 = c2 + 3 + dl;
#pragma unroll
    for (int r = 0; r < KNN; ++r) f2v[r] = f2[16 * r];
  }
  const float n2 = qx * qx + qy * qy + qz * qz;

  float dist[KNN]; int nidx[KNN];
#pragma unroll
  for (int k = 0; k < KNN; ++k) { dist[k] = INFINITY; nidx[k] = 0; }

  // Scan this query's batch range directly from the compact global table.
  for (int j = qs + sub; j < qe; j += SUB) {
    float4 c = c4[j];
    float d = fmaf(-2.0f, fmaf(qx, c.x, fmaf(qy, c.y, qz * c.z)), n2 + c.w);
    d = fmaxf(d, 0.0f);
    // strict < : ascending j => ties keep earlier index within a slice
    if (d < dist[KNN - 1]) {
      dist[KNN - 1] = d; nidx[KNN - 1] = j;
#pragma unroll
      for (int k = KNN - 1; k > 0; --k) {
        if (dist[k] < dist[k - 1]) {
          float td = dist[k]; dist[k] = dist[k - 1]; dist[k - 1] = td;
          int ti = nidx[k]; nidx[k] = nidx[k - 1]; nidx[k - 1] = ti;
        }
      }
    }
  }

  // Fused exact merge + gather across each 16-lane group. Round r extracts
  // the lexicographic (d, idx) min (butterfly => converged in every lane),
  // then immediately accumulates that neighbor's features for this lane's
  // 8 owned dims. Padded (inf,0) entries contribute w=0 * x1-row-0 = 0.
  float acc[KNN];
#pragma unroll
  for (int t = 0; t < KNN; ++t) acc[t] = 0.f;
  float sw = 0.f;
#pragma unroll
  for (int r = 0; r < KNN; ++r) {
    float hd = dist[0]; int hidx = nidx[0];
    float bd = hd; int bi = hidx;
#pragma unroll
    for (int m = 1; m <= 8; m <<= 1) {
      float od = __shfl_xor(bd, m); int oi = __shfl_xor(bi, m);
      if (od < bd || (od == bd && oi < bi)) { bd = od; bi = oi; }
    }
    if (hd == bd && hidx == bi) {   // pop winner (unique for real entries)
#pragma unroll
      for (int k = 0; k < KNN - 1; ++k) { dist[k] = dist[k + 1]; nidx[k] = nidx[k + 1]; }
      dist[KNN - 1] = INFINITY; nidx[KNN - 1] = 0;
    }
    float w = 1.0f / fmaxf(bd, 1e-16f);   // d=inf (pad) -> w = 0
    sw += w;
    const float* f = x1 + (size_t)bi * ROW + 3 + dl;
#pragma unroll
    for (int t = 0; t < KNN; ++t) acc[t] = fmaf(w, f[16 * t], acc[t]);
  }

  float pacc = 0.0f;
  if (q < N) {
    float rinv = 1.0f / sw;
#pragma unroll
    for (int t = 0; t < KNN; ++t) {
      float e = fmaf(acc[t], rinv, -f2v[t]);
      pacc += e * e;
    }
  }
  // Wave total (sums the wave's 4 queries' partials; fixed order).
#pragma unroll
  for (int off = 32; off > 0; off >>= 1) pacc += __shfl_xor(pacc, off);
  if (lane == 0) wred[wv] = pacc;
  __syncthreads();
  if (tid == 0) {
    float s = (wred[0] + wred[1]) + (wred[2] + wred[3]);
    ws_part[blockIdx.x] = s;
  }
}

// Kernel C: deterministic final reduction + mean scale.
__global__ void knn_final(const float* __restrict__ part, int n,
                          float scale, float* __restrict__ out) {
  __shared__ float sm[256];
  float s = 0.0f;
  for (int i = threadIdx.x; i < n; i += 256) s += part[i];
  sm[threadIdx.x] = s;
  __syncthreads();
  for (int step = 128; step > 0; step >>= 1) {
    if (threadIdx.x < step) sm[threadIdx.x] += sm[threadIdx.x + step];
    __syncthreads();
  }
  if (threadIdx.x == 0) out[0] = sm[0] * scale;
}

extern "C" void kernel_launch(void* const* d_in, const int* in_sizes, int n_in,
                              void* d_out, int out_size, void* d_ws, size_t ws_size,
                              hipStream_t stream) {
  const float* x1 = (const float*)d_in[0];
  const float* x2 = (const float*)d_in[1];
  const int* b1 = (const int*)d_in[2];
  const int* b2 = (const int*)d_in[3];
  int N = in_sizes[2];            // 16384
  int ROW = in_sizes[0] / N;      // 131
  float* out = (float*)d_out;

  int blocks = (N + QPB - 1) / QPB;              // 1024

  // ws layout: c4 compact | s1 table | partials
  char* base = (char*)d_ws;
  float4* c4 = (float4*)base;
  int* s1 = (int*)(base + (size_t)N * sizeof(float4));
  float* ws_part = (float*)(base + (size_t)N * sizeof(float4) + 2048);
  size_t need = (size_t)N * sizeof(float4) + 2048 + (size_t)blocks * sizeof(float);
  if (ws_size < need) return;     // fail visibly rather than corrupt

  knn_prep<<<(N + 255) / 256, 256, 0, stream>>>(x1, b1, N, ROW, c4, s1);
  knn_main<<<blocks, BLK, 0, stream>>>(c4, x1, x2, b2, s1, N, ROW, ws_part);
  float scale = 1.0f / ((float)N * (float)(ROW - 3));
  knn_final<<<1, 256, 0, stream>>>(ws_part, blocks, scale, out);
}

// Round 9
// 39.343 us; speedup vs baseline: 1.0423x; 1.0423x over previous
//
#include <hip/hip_runtime.h>
#include <math.h>

#define KNN 8
#define SUB 16          // lanes per query in select
#define BLK 256
#define NBMAX 256       // batch-id table capacity

// K1: compact {x,y,z,|c|^2} for every x1 row + lower-bound table for b1.
// s1[b] = first index i with b1[i] >= b (b1 sorted; unique writer per entry).
__global__ void knn_prep(const float* __restrict__ x1,
                         const int* __restrict__ b1,
                         int N, int ROW,
                         float4* __restrict__ c4,
                         int* __restrict__ s1) {
  int i = blockIdx.x * blockDim.x + threadIdx.x;
  if (i >= N) return;
  const float* p = x1 + (size_t)i * ROW;
  float x = p[0], y = p[1], z = p[2];
  c4[i] = make_float4(x, y, z, x * x + y * y + z * z);
  int bc = b1[i];
  int bp = (i == 0) ? -1 : b1[i - 1];
  for (int b = bp + 1; b <= bc; ++b) s1[b] = i;
  if (i == N - 1) { for (int b = bc + 1; b <= NBMAX + 1; ++b) s1[b] = N; }
}

// K2: top-8 select. 16 lanes per query scan the dense c4 table (contiguous
// 256B per group per iteration; same-batch groups broadcast). Branchless
// predicated sorted-insert; exact lexicographic (d, idx) shuffle merge
// (masks 1,2,4,8); round-r winner stored by lane sub==r (64B/query).
__launch_bounds__(BLK, 4)
__global__ void knn_select(const float4* __restrict__ c4,
                           const float* __restrict__ x2,
                           const int* __restrict__ b2,
                           const int* __restrict__ s1,
                           int N, int ROW,
                           float2* __restrict__ pairs) {
  const int tid = threadIdx.x;
  const int sub = tid & (SUB - 1);
  const int q   = blockIdx.x * (BLK / SUB) + (tid >> 4);

  float qx = 0.f, qy = 0.f, qz = 0.f; int qs = 0, qe = 0;
  if (q < N) {
    const float* c2 = x2 + (size_t)q * ROW;
    qx = c2[0]; qy = c2[1]; qz = c2[2];
    int b = b2[q];
    qs = s1[b]; qe = s1[b + 1];
  }
  const float n2 = qx * qx + qy * qy + qz * qz;

  float dist[KNN]; int nidx[KNN];
#pragma unroll
  for (int k = 0; k < KNN; ++k) { dist[k] = INFINITY; nidx[k] = 0; }

  for (int j = qs + sub; j < qe; j += SUB) {
    float4 c = c4[j];
    float d = fmaxf(fmaf(-2.0f, fmaf(qx, c.x, fmaf(qy, c.y, qz * c.z)), n2 + c.w), 0.0f);
    // Branchless sorted insert, strict < (ascending j => per-lane ties keep
    // the earlier index, matching jax.lax.top_k).
    bool lt[KNN];
#pragma unroll
    for (int k = 0; k < KNN; ++k) lt[k] = d < dist[k];
#pragma unroll
    for (int k = KNN - 1; k > 0; --k) {
      dist[k] = lt[k - 1] ? dist[k - 1] : (lt[k] ? d : dist[k]);
      nidx[k] = lt[k - 1] ? nidx[k - 1] : (lt[k] ? j : nidx[k]);
    }
    dist[0] = lt[0] ? d : dist[0];
    nidx[0] = lt[0] ? j : nidx[0];
  }

  // Exact 16-way merge: round r extracts the lexicographic (d, idx) min
  // across the 16-lane group (butterfly => converged in every lane).
#pragma unroll
  for (int r = 0; r < KNN; ++r) {
    float hd = dist[0]; int hx = nidx[0];
    float bd = hd; int bi = hx;
#pragma unroll
    for (int m = 1; m <= 8; m <<= 1) {
      float od = __shfl_xor(bd, m); int oi = __shfl_xor(bi, m);
      if (od < bd || (od == bd && oi < bi)) { bd = od; bi = oi; }
    }
    if (hd == bd && hx == bi) {   // pop winner (unique for real entries;
                                  // (inf,0) pads multi-pop harmlessly)
#pragma unroll
      for (int k = 0; k < KNN - 1; ++k) { dist[k] = dist[k + 1]; nidx[k] = nidx[k + 1]; }
      dist[KNN - 1] = INFINITY; nidx[KNN - 1] = 0;
    }
    if (sub == r && q < N)
      pairs[(size_t)q * KNN + r] = make_float2(bd, __int_as_float(bi));
  }
}

// K3: gather + MSE. One wave per query: 64B pair block broadcast-read, then
// 16 independent coalesced feature loads; lane l owns dims l and l+64.
__launch_bounds__(BLK, 4)
__global__ void knn_gather(const float2* __restrict__ pairs,
                           const float* __restrict__ x1,
                           const float* __restrict__ x2,
                           int N, int ROW,
                           float* __restrict__ ws_part) {
  __shared__ float wred[BLK / 64];
  const int tid = threadIdx.x, lane = tid & 63, wv = tid >> 6;
  const int q = blockIdx.x * (BLK / 64) + wv;
  float pacc = 0.0f;
  if (q < N) {
    const float4* pp = (const float4*)(pairs + (size_t)q * KNN);
    float4 p01 = pp[0], p23 = pp[1], p45 = pp[2], p67 = pp[3];
    float dd[KNN] = {p01.x, p01.z, p23.x, p23.z, p45.x, p45.z, p67.x, p67.z};
    int   id[KNN] = {__float_as_int(p01.y), __float_as_int(p01.w),
                     __float_as_int(p23.y), __float_as_int(p23.w),
                     __float_as_int(p45.y), __float_as_int(p45.w),
                     __float_as_int(p67.y), __float_as_int(p67.w)};
    float w[KNN]; float sw = 0.0f;
#pragma unroll
    for (int r = 0; r < KNN; ++r) { w[r] = 1.0f / fmaxf(dd[r], 1e-16f); sw += w[r]; }
    float acc0 = 0.0f, acc1 = 0.0f;
#pragma unroll
    for (int r = 0; r < KNN; ++r) {
      const float* f = x1 + (size_t)id[r] * ROW + 3;
      acc0 = fmaf(w[r], f[lane], acc0);
      acc1 = fmaf(w[r], f[lane + 64], acc1);
    }
    const float* f2 = x2 + (size_t)q * ROW + 3;
    float rinv = 1.0f / sw;
    float e0 = fmaf(acc0, rinv, -f2[lane]);
    float e1 = fmaf(acc1, rinv, -f2[lane + 64]);
    pacc = e0 * e0 + e1 * e1;
  }
#pragma unroll
  for (int off = 32; off > 0; off >>= 1) pacc += __shfl_xor(pacc, off);
  if (lane == 0) wred[wv] = pacc;
  __syncthreads();
  if (tid == 0)
    ws_part[blockIdx.x] = (wred[0] + wred[1]) + (wred[2] + wred[3]);
}

// K4: deterministic final reduction + mean scale.
__global__ void knn_final(const float* __restrict__ part, int n,
                          float scale, float* __restrict__ out) {
  __shared__ float sm[256];
  float s = 0.0f;
  for (int i = threadIdx.x; i < n; i += 256) s += part[i];
  sm[threadIdx.x] = s;
  __syncthreads();
  for (int step = 128; step > 0; step >>= 1) {
    if (threadIdx.x < step) sm[threadIdx.x] += sm[threadIdx.x + step];
    __syncthreads();
  }
  if (threadIdx.x == 0) out[0] = sm[0] * scale;
}

extern "C" void kernel_launch(void* const* d_in, const int* in_sizes, int n_in,
                              void* d_out, int out_size, void* d_ws, size_t ws_size,
                              hipStream_t stream) {
  const float* x1 = (const float*)d_in[0];
  const float* x2 = (const float*)d_in[1];
  const int* b1 = (const int*)d_in[2];
  const int* b2 = (const int*)d_in[3];
  int N = in_sizes[2];            // 16384
  int ROW = in_sizes[0] / N;      // 131
  float* out = (float*)d_out;

  // ws layout: c4 | s1 | pairs | partials
  char* base = (char*)d_ws;
  size_t off_c4 = 0;
  size_t off_s1 = off_c4 + (size_t)N * sizeof(float4);
  size_t off_pr = off_s1 + 2048;
  size_t off_pt = off_pr + (size_t)N * KNN * sizeof(float2);
  float4* c4 = (float4*)(base + off_c4);
  int* s1 = (int*)(base + off_s1);
  float2* pairs = (float2*)(base + off_pr);
  float* ws_part = (float*)(base + off_pt);

  int blocks_sel = (N * SUB + BLK - 1) / BLK;    // 1024
  int blocks_gth = (N * 64 + BLK - 1) / BLK;     // 4096
  size_t need = off_pt + (size_t)blocks_gth * sizeof(float);
  if (ws_size < need) return;     // fail visibly rather than corrupt

  knn_prep<<<(N + 127) / 128, 128, 0, stream>>>(x1, b1, N, ROW, c4, s1);
  knn_select<<<blocks_sel, BLK, 0, stream>>>(c4, x2, b2, s1, N, ROW, pairs);
  knn_gather<<<blocks_gth, BLK, 0, stream>>>(pairs, x1, x2, N, ROW, ws_part);
  float scale = 1.0f / ((float)N * (float)(ROW - 3));
  knn_final<<<1, 256, 0, stream>>>(ws_part, blocks_gth, scale, out);
}

// Round 10
// 30.444 us; speedup vs baseline: 1.3470x; 1.2923x over previous
//
#include <hip/hip_runtime.h>
#include <math.h>

#define KNN 8
#define QPB 32          // queries per block
#define SUB 16          // sub-lanes per query
#define BLK 512         // QPB*SUB threads, 8 waves
#define CAP 1024        // staged candidates per LDS tile (>= 2 full batches)
#define NBMAX 256       // batch-id table capacity

// K1: s1[b] = first index i with b1[i] >= b (b1 sorted; unique writer/entry).
__global__ void knn_prep(const int* __restrict__ b1, int N,
                         int* __restrict__ s1) {
  int i = blockIdx.x * blockDim.x + threadIdx.x;
  if (i >= N) return;
  int bc = b1[i];
  int bp = (i == 0) ? -1 : b1[i - 1];
  for (int b = bp + 1; b <= bc; ++b) s1[b] = i;
  if (i == N - 1) { for (int b = bc + 1; b <= NBMAX + 1; ++b) s1[b] = N; }
}

// K2: fused select+gather, R4 skeleton minus all per-block search/tables.
// Stage batch coords into LDS -> 16-way sliced branchless top-8 scan ->
// exact lexicographic (d, idx) shuffle merge -> LDS nbrs -> per-wave gather
// + MSE partial. One deterministic partial per block. No fences/atomics.
__launch_bounds__(BLK, 4)
__global__ void knn_main(const float* __restrict__ x1,
                         const float* __restrict__ x2,
                         const int* __restrict__ b2,
                         const int* __restrict__ s1g,
                         int N, int ROW,
                         float* __restrict__ ws_part) {
  __shared__ float4 c4[CAP];          // {x, y, z, |c|^2}
  __shared__ float2 nbrs[QPB][KNN];   // merged (d, idx) per query
  __shared__ int   s_info[2];         // block staging range {s1, e1}
  __shared__ float wred[BLK / 64];

  const int tid  = threadIdx.x;
  const int lane = tid & 63;
  const int wv   = tid >> 6;          // 0..7
  const int qi   = tid >> 4;          // 0..31 query within block
  const int sub  = tid & (SUB - 1);
  const int q0   = blockIdx.x * QPB;
  const int q    = q0 + qi;
  const int qlast = min(q0 + QPB - 1, N - 1);

  // Block-uniform staging range via the prep table: 2 dependent loads.
  if (tid < 2) {
    int qq = (tid == 0) ? q0 : qlast;
    s_info[tid] = s1g[b2[qq] + tid];  // tid0: s1[b_first], tid1: s1[b_last+1]
  }

  // Per-query data (b2/s1 reads broadcast within a batch).
  float qx = 0.f, qy = 0.f, qz = 0.f; int qs = 0, qe = 0;
  if (q < N) {
    const float* c2 = x2 + (size_t)q * ROW;
    qx = c2[0]; qy = c2[1]; qz = c2[2];
    int mb = b2[q];
    qs = s1g[mb]; qe = s1g[mb + 1];
  }
  const float n2 = qx * qx + qy * qy + qz * qz;

  float dist[KNN]; int nidx[KNN];
#pragma unroll
  for (int k = 0; k < KNN; ++k) { dist[k] = INFINITY; nidx[k] = 0; }

  __syncthreads();
  const int s1v = s_info[0], e1v = s_info[1];

  for (int t0 = s1v; t0 < e1v; t0 += CAP) {
    const int t1 = min(t0 + CAP, e1v);
    __syncthreads();                   // c4 reuse guard (uniform trip count)
    for (int i = t0 + tid; i < t1; i += BLK) {
      const float* p = x1 + (size_t)i * ROW;
      float cx = p[0], cy = p[1], cz = p[2];
      c4[i - t0] = make_float4(cx, cy, cz, cx * cx + cy * cy + cz * cz);
    }
    __syncthreads();
    const int lo = max(qs, t0), hi = min(qe, t1);
    for (int j = lo + sub; j < hi; j += SUB) {
      float4 c = c4[j - t0];
      float d = fmaxf(fmaf(-2.0f, fmaf(qx, c.x, fmaf(qy, c.y, qz * c.z)), n2 + c.w), 0.0f);
      // Branchless sorted insert, strict < (ascending j => per-lane ties
      // keep the earlier index, matching jax.lax.top_k).
      bool lt[KNN];
#pragma unroll
      for (int k = 0; k < KNN; ++k) lt[k] = d < dist[k];
#pragma unroll
      for (int k = KNN - 1; k > 0; --k) {
        dist[k] = lt[k - 1] ? dist[k - 1] : (lt[k] ? d : dist[k]);
        nidx[k] = lt[k - 1] ? nidx[k - 1] : (lt[k] ? j : nidx[k]);
      }
      dist[0] = lt[0] ? d : dist[0];
      nidx[0] = lt[0] ? j : nidx[0];
    }
  }

  // Exact 16-way merge: round r extracts the lexicographic (d, idx) min
  // across the 16-lane group (butterfly => converged in every lane).
#pragma unroll
  for (int r = 0; r < KNN; ++r) {
    float hd = dist[0]; int hx = nidx[0];
    float bd = hd; int bi = hx;
#pragma unroll
    for (int m = 1; m <= 8; m <<= 1) {
      float od = __shfl_xor(bd, m); int oi = __shfl_xor(bi, m);
      if (od < bd || (od == bd && oi < bi)) { bd = od; bi = oi; }
    }
    if (hd == bd && hx == bi) {   // pop winner (unique for real entries;
                                  // (inf,0) pads multi-pop harmlessly)
#pragma unroll
      for (int k = 0; k < KNN - 1; ++k) { dist[k] = dist[k + 1]; nidx[k] = nidx[k + 1]; }
      dist[KNN - 1] = INFINITY; nidx[KNN - 1] = 0;
    }
    if (sub == r && q < N)
      nbrs[qi][r] = make_float2(bd, __int_as_float(bi));
  }
  __syncthreads();

  // Gather + MSE: wave wv owns queries q0+4*wv..+3; neighbor lists via
  // broadcast ds_read_b128; lane l owns dims l and l+64.
  float pacc = 0.0f;
#pragma unroll
  for (int qq = 0; qq < QPB / (BLK / 64); ++qq) {
    const int lq = wv * (QPB / (BLK / 64)) + qq;
    const int gq = q0 + lq;
    if (gq < N) {                      // wave-uniform
      const float4* pn = (const float4*)&nbrs[lq][0];
      float4 n01 = pn[0], n23 = pn[1], n45 = pn[2], n67 = pn[3];
      float dd[KNN] = {n01.x, n01.z, n23.x, n23.z, n45.x, n45.z, n67.x, n67.z};
      int   id[KNN] = {__float_as_int(n01.y), __float_as_int(n01.w),
                       __float_as_int(n23.y), __float_as_int(n23.w),
                       __float_as_int(n45.y), __float_as_int(n45.w),
                       __float_as_int(n67.y), __float_as_int(n67.w)};
      float w[KNN]; float sw = 0.0f;
#pragma unroll
      for (int r = 0; r < KNN; ++r) { w[r] = 1.0f / fmaxf(dd[r], 1e-16f); sw += w[r]; }
      float acc0 = 0.0f, acc1 = 0.0f;
#pragma unroll
      for (int r = 0; r < KNN; ++r) {
        const float* f = x1 + (size_t)id[r] * ROW + 3;
        acc0 = fmaf(w[r], f[lane], acc0);
        acc1 = fmaf(w[r], f[lane + 64], acc1);
      }
      const float* f2 = x2 + (size_t)gq * ROW + 3;
      float rinv = 1.0f / sw;
      float e0 = fmaf(acc0, rinv, -f2[lane]);
      float e1 = fmaf(acc1, rinv, -f2[lane + 64]);
      pacc += e0 * e0 + e1 * e1;
    }
  }
#pragma unroll
  for (int off = 32; off > 0; off >>= 1) pacc += __shfl_xor(pacc, off);
  if (lane == 0) wred[wv] = pacc;
  __syncthreads();
  if (tid == 0) {
    float s = 0.0f;
#pragma unroll
    for (int w = 0; w < BLK / 64; ++w) s += wred[w];
    ws_part[blockIdx.x] = s;
  }
}

// K3: deterministic final reduction + mean scale.
__global__ void knn_final(const float* __restrict__ part, int n,
                          float scale, float* __restrict__ out) {
  __shared__ float sm[256];
  float s = 0.0f;
  for (int i = threadIdx.x; i < n; i += 256) s += part[i];
  sm[threadIdx.x] = s;
  __syncthreads();
  for (int step = 128; step > 0; step >>= 1) {
    if (threadIdx.x < step) sm[threadIdx.x] += sm[threadIdx.x + step];
    __syncthreads();
  }
  if (threadIdx.x == 0) out[0] = sm[0] * scale;
}

extern "C" void kernel_launch(void* const* d_in, const int* in_sizes, int n_in,
                              void* d_out, int out_size, void* d_ws, size_t ws_size,
                              hipStream_t stream) {
  const float* x1 = (const float*)d_in[0];
  const float* x2 = (const float*)d_in[1];
  const int* b1 = (const int*)d_in[2];
  const int* b2 = (const int*)d_in[3];
  int N = in_sizes[2];            // 16384
  int ROW = in_sizes[0] / N;      // 131
  float* out = (float*)d_out;

  int blocks = (N + QPB - 1) / QPB;              // 512

  // ws layout: s1 table (2048B) | partials
  char* base = (char*)d_ws;
  int* s1 = (int*)base;
  float* ws_part = (float*)(base + 2048);
  size_t need = 2048 + (size_t)blocks * sizeof(float);
  if (ws_size < need) return;     // fail visibly rather than corrupt

  knn_prep<<<(N + 255) / 256, 256, 0, stream>>>(b1, N, s1);
  knn_main<<<blocks, BLK, 0, stream>>>(x1, x2, b2, s1, N, ROW, ws_part);
  float scale = 1.0f / ((float)N * (float)(ROW - 3));
  knn_final<<<1, 256, 0, stream>>>(ws_part, blocks, scale, out);
}

// Round 11
// 29.121 us; speedup vs baseline: 1.4081x; 1.0454x over previous
//
#include <hip/hip_runtime.h>
#include <math.h>

#define KNN 8
#define QPB 32          // queries per block
#define SUB 16          // sub-lanes per query
#define BLK 512         // QPB*SUB threads, 8 waves
#define CAP 1024        // staged candidates per LDS tile

// Single fused kernel, single dispatch.
//   waves 0-1: cooperative range search on b1 (64-ary, ~3 dependent rounds)
//   stage {x,y,z,|c|^2} + batch-id into LDS
//   16-way sliced scan with batch-mask, branchless sorted top-8 insert
//   exact lexicographic (d, idx) shuffle pop-merge -> nbrs in LDS
//   per-wave gather + MSE partial -> block reduce
//   block writes {TAG|partial} as ONE 64-bit agent-scope relaxed atomic store
//   block 0 / wave 0 spin-reads all slots (values are deterministic, so any
//   interleaving is bit-identical), fixed-order sum -> out[0].
// No fences, no L2 invalidates, no cross-call state.
__launch_bounds__(BLK, 4)
__global__ void knn_one(const float* __restrict__ x1,
                        const float* __restrict__ x2,
                        const int* __restrict__ b1,
                        const int* __restrict__ b2,
                        int N, int ROW, float scale,
                        unsigned long long* __restrict__ slot,
                        float* __restrict__ out) {
  __shared__ float4 c4[CAP];          // {x, y, z, |c|^2}
  __shared__ int   bs[CAP];           // batch id per staged row
  __shared__ int   s_info[2];         // block staging range {s1, e1}
  __shared__ float wred[BLK / 64];

  const int tid  = threadIdx.x;
  const int lane = tid & 63;
  const int wv   = tid >> 6;          // 0..7
  const int qi   = tid >> 4;          // 0..31 query within block
  const int sub  = tid & (SUB - 1);
  const int q0   = blockIdx.x * QPB;
  const int q    = min(q0 + qi, N - 1);
  const int qlast = min(q0 + QPB - 1, N - 1);

  // Wave-cooperative lower_bound on b1 (64-way fanout). Invariant: lb in [lo,hi].
  if (wv < 2) {
    const int bb = (wv == 0) ? b2[q0] : b2[qlast];
    const int target = bb + wv;       // wv0: lb(b_first), wv1: lb(b_last+1)
    int lo = 0, hi = N;
    while (lo < hi) {
      int step = (hi - lo + 63) >> 6;
      int p = lo + lane * step;
      bool pred = (p < hi) && (b1[p] < target);
      int c = __popcll(__ballot(pred));
      if (c == 0) { hi = lo; break; }
      int nlo = lo + (c - 1) * step + 1;
      hi = min(hi, lo + c * step);
      lo = nlo;
    }
    if (lane == 0) s_info[wv] = lo;
  }

  float qx, qy, qz; int mybatch;
  {
    const float* c2 = x2 + (size_t)q * ROW;
    qx = c2[0]; qy = c2[1]; qz = c2[2];
    mybatch = b2[q];
  }
  const float n2 = qx * qx + qy * qy + qz * qz;

  float dist[KNN]; int nidx[KNN];
#pragma unroll
  for (int k = 0; k < KNN; ++k) { dist[k] = INFINITY; nidx[k] = 0; }

  __syncthreads();
  const int s1v = s_info[0], e1v = s_info[1];

  for (int t0 = s1v; t0 < e1v; t0 += CAP) {
    const int t1 = min(t0 + CAP, e1v);
    __syncthreads();                   // c4/bs reuse guard (uniform trip count)
    for (int i = t0 + tid; i < t1; i += BLK) {
      const float* p = x1 + (size_t)i * ROW;
      float cx = p[0], cy = p[1], cz = p[2];
      c4[i - t0] = make_float4(cx, cy, cz, cx * cx + cy * cy + cz * cz);
      bs[i - t0] = b1[i];
    }
    __syncthreads();
    // All lanes scan the whole tile; foreign-batch rows masked to INF
    // (never inserted: INF < dist[7] is false). Uniform trip count per group.
    for (int j = t0 + sub; j < t1; j += SUB) {
      float4 c = c4[j - t0];
      int bv = bs[j - t0];
      float d = fmaxf(fmaf(-2.0f, fmaf(qx, c.x, fmaf(qy, c.y, qz * c.z)), n2 + c.w), 0.0f);
      d = (bv == mybatch) ? d : INFINITY;
      // Branchless sorted insert, strict < (ascending j => per-lane ties keep
      // the earlier index, matching jax.lax.top_k).
      bool lt[KNN];
#pragma unroll
      for (int k = 0; k < KNN; ++k) lt[k] = d < dist[k];
#pragma unroll
      for (int k = KNN - 1; k > 0; --k) {
        dist[k] = lt[k - 1] ? dist[k - 1] : (lt[k] ? d : dist[k]);
        nidx[k] = lt[k - 1] ? nidx[k - 1] : (lt[k] ? j : nidx[k]);
      }
      dist[0] = lt[0] ? d : dist[0];
      nidx[0] = lt[0] ? j : nidx[0];
    }
  }

  // Exact 16-way pop-merge: round r extracts the lexicographic (d, idx) min
  // across the 16-lane group (butterfly => converged in every lane).
  __shared__ float2 nbrs[QPB][KNN];
#pragma unroll
  for (int r = 0; r < KNN; ++r) {
    float hd = dist[0]; int hx = nidx[0];
    float bd = hd; int bi = hx;
#pragma unroll
    for (int m = 1; m <= 8; m <<= 1) {
      float od = __shfl_xor(bd, m); int oi = __shfl_xor(bi, m);
      if (od < bd || (od == bd && oi < bi)) { bd = od; bi = oi; }
    }
    if (hd == bd && hx == bi) {   // pop winner; (inf,0) pads multi-pop harmlessly
#pragma unroll
      for (int k = 0; k < KNN - 1; ++k) { dist[k] = dist[k + 1]; nidx[k] = nidx[k + 1]; }
      dist[KNN - 1] = INFINITY; nidx[KNN - 1] = 0;
    }
    if (sub == r)
      nbrs[qi][r] = make_float2(bd, __int_as_float(bi));
  }
  __syncthreads();

  // Gather + MSE: wave wv owns queries q0+4*wv..+3; neighbor lists via
  // broadcast ds_read_b128; lane l owns dims l and l+64.
  float pacc = 0.0f;
#pragma unroll
  for (int qq = 0; qq < QPB / (BLK / 64); ++qq) {
    const int lq = wv * (QPB / (BLK / 64)) + qq;
    const int gq = q0 + lq;
    if (gq < N) {                      // wave-uniform
      const float4* pn = (const float4*)&nbrs[lq][0];
      float4 n01 = pn[0], n23 = pn[1], n45 = pn[2], n67 = pn[3];
      float dd[KNN] = {n01.x, n01.z, n23.x, n23.z, n45.x, n45.z, n67.x, n67.z};
      int   id[KNN] = {__float_as_int(n01.y), __float_as_int(n01.w),
                       __float_as_int(n23.y), __float_as_int(n23.w),
                       __float_as_int(n45.y), __float_as_int(n45.w),
                       __float_as_int(n67.y), __float_as_int(n67.w)};
      float w[KNN]; float sw = 0.0f;
#pragma unroll
      for (int r = 0; r < KNN; ++r) { w[r] = 1.0f / fmaxf(dd[r], 1e-16f); sw += w[r]; }
      float acc0 = 0.0f, acc1 = 0.0f;
#pragma unroll
      for (int r = 0; r < KNN; ++r) {
        const float* f = x1 + (size_t)id[r] * ROW + 3;
        acc0 = fmaf(w[r], f[lane], acc0);
        acc1 = fmaf(w[r], f[lane + 64], acc1);
      }
      const float* f2 = x2 + (size_t)gq * ROW + 3;
      float rinv = 1.0f / sw;
      float e0 = fmaf(acc0, rinv, -f2[lane]);
      float e1 = fmaf(acc1, rinv, -f2[lane + 64]);
      pacc += e0 * e0 + e1 * e1;
    }
  }
#pragma unroll
  for (int off = 32; off > 0; off >>= 1) pacc += __shfl_xor(pacc, off);
  if (lane == 0) wred[wv] = pacc;
  __syncthreads();

  // Publish {TAG(bid) | partial} as one 64-bit coherent relaxed store.
  if (tid == 0) {
    float s = 0.0f;
#pragma unroll
    for (int w = 0; w < BLK / 64; ++w) s += wred[w];
    unsigned long long v =
        ((unsigned long long)(0x5A000000u | (unsigned)blockIdx.x) << 32) |
        (unsigned long long)__float_as_uint(s);
    __hip_atomic_store(&slot[blockIdx.x], v, __ATOMIC_RELAXED,
                       __HIP_MEMORY_SCOPE_AGENT);
  }

  // Block 0 / wave 0: spin-read all slots (deterministic values => any
  // interleaving is bit-identical), fixed-order sum, write result.
  if (blockIdx.x == 0 && wv == 0) {
    const int nblk = (int)gridDim.x;
    float s = 0.0f;
    for (int r = 0; r * 64 + lane < nblk; ++r) {
      int i = r * 64 + lane;
      unsigned tag = 0x5A000000u | (unsigned)i;
      unsigned long long x = __hip_atomic_load(&slot[i], __ATOMIC_RELAXED,
                                               __HIP_MEMORY_SCOPE_AGENT);
      while ((unsigned)(x >> 32) != tag) {
        __builtin_amdgcn_s_sleep(8);
        x = __hip_atomic_load(&slot[i], __ATOMIC_RELAXED,
                              __HIP_MEMORY_SCOPE_AGENT);
      }
      s += __uint_as_float((unsigned)x);   // lane-local, fixed r-order
    }
#pragma unroll
    for (int off = 32; off > 0; off >>= 1) s += __shfl_xor(s, off);
    if (lane == 0) out[0] = s * scale;
  }
}

extern "C" void kernel_launch(void* const* d_in, const int* in_sizes, int n_in,
                              void* d_out, int out_size, void* d_ws, size_t ws_size,
                              hipStream_t stream) {
  const float* x1 = (const float*)d_in[0];
  const float* x2 = (const float*)d_in[1];
  const int* b1 = (const int*)d_in[2];
  const int* b2 = (const int*)d_in[3];
  int N = in_sizes[2];            // 16384
  int ROW = in_sizes[0] / N;      // 131
  float* out = (float*)d_out;

  int blocks = (N + QPB - 1) / QPB;              // 512
  unsigned long long* slot = (unsigned long long*)d_ws;
  if (ws_size < (size_t)blocks * sizeof(unsigned long long)) return;

  float scale = 1.0f / ((float)N * (float)(ROW - 3));
  knn_one<<<blocks, BLK, 0, stream>>>(x1, x2, b1, b2, N, ROW, scale, slot, out);
}

// Round 12
// 27.304 us; speedup vs baseline: 1.5018x; 1.0665x over previous
//
#include <hip/hip_runtime.h>
#include <math.h>

#define KNN 8
#define QPB 32          // queries per block
#define SUB 16          // sub-lanes per query
#define BLK 512         // QPB*SUB threads, 8 waves
#define CAP 1024        // staged candidates per LDS tile

// Single fused kernel, single dispatch. Identical to R11 except for the
// bijective XCD-aware block swizzle (T1): hardware assigns XCD = hwbid % 8,
// so remap work-ids so that consecutive work blocks (which share a batch's
// coord sectors and feature rows) land on the SAME XCD's L2 instead of
// being duplicated across all 8.
__launch_bounds__(BLK, 4)
__global__ void knn_one(const float* __restrict__ x1,
                        const float* __restrict__ x2,
                        const int* __restrict__ b1,
                        const int* __restrict__ b2,
                        int N, int ROW, float scale,
                        unsigned long long* __restrict__ slot,
                        float* __restrict__ out) {
  __shared__ float4 c4[CAP];          // {x, y, z, |c|^2}
  __shared__ int   bs[CAP];           // batch id per staged row
  __shared__ int   s_info[2];         // block staging range {s1, e1}
  __shared__ float2 nbrs[QPB][KNN];   // merged (d, idx) per query
  __shared__ float wred[BLK / 64];

  // Bijective XCD swizzle (m204 variant): xcd = hw%8 stays fixed, so all
  // work-ids in one contiguous chunk run on one XCD.
  const int nwg = (int)gridDim.x;
  const int xcd = (int)blockIdx.x & 7, pos = (int)blockIdx.x >> 3;
  const int q8 = nwg >> 3, r8 = nwg & 7;
  const int bid = (xcd < r8) ? xcd * (q8 + 1) + pos
                             : r8 * (q8 + 1) + (xcd - r8) * q8 + pos;

  const int tid  = threadIdx.x;
  const int lane = tid & 63;
  const int wv   = tid >> 6;          // 0..7
  const int qi   = tid >> 4;          // 0..31 query within block
  const int sub  = tid & (SUB - 1);
  const int q0   = bid * QPB;
  const int q    = min(q0 + qi, N - 1);
  const int qlast = min(q0 + QPB - 1, N - 1);

  // Wave-cooperative lower_bound on b1 (64-way fanout). Invariant: lb in [lo,hi].
  if (wv < 2) {
    const int bb = (wv == 0) ? b2[q0] : b2[qlast];
    const int target = bb + wv;       // wv0: lb(b_first), wv1: lb(b_last+1)
    int lo = 0, hi = N;
    while (lo < hi) {
      int step = (hi - lo + 63) >> 6;
      int p = lo + lane * step;
      bool pred = (p < hi) && (b1[p] < target);
      int c = __popcll(__ballot(pred));
      if (c == 0) { hi = lo; break; }
      int nlo = lo + (c - 1) * step + 1;
      hi = min(hi, lo + c * step);
      lo = nlo;
    }
    if (lane == 0) s_info[wv] = lo;
  }

  float qx, qy, qz; int mybatch;
  {
    const float* c2 = x2 + (size_t)q * ROW;
    qx = c2[0]; qy = c2[1]; qz = c2[2];
    mybatch = b2[q];
  }
  const float n2 = qx * qx + qy * qy + qz * qz;

  float dist[KNN]; int nidx[KNN];
#pragma unroll
  for (int k = 0; k < KNN; ++k) { dist[k] = INFINITY; nidx[k] = 0; }

  __syncthreads();
  const int s1v = s_info[0], e1v = s_info[1];

  for (int t0 = s1v; t0 < e1v; t0 += CAP) {
    const int t1 = min(t0 + CAP, e1v);
    __syncthreads();                   // c4/bs reuse guard (uniform trip count)
    for (int i = t0 + tid; i < t1; i += BLK) {
      const float* p = x1 + (size_t)i * ROW;
      float cx = p[0], cy = p[1], cz = p[2];
      c4[i - t0] = make_float4(cx, cy, cz, cx * cx + cy * cy + cz * cz);
      bs[i - t0] = b1[i];
    }
    __syncthreads();
    // All lanes scan the whole tile; foreign-batch rows masked to INF
    // (never inserted: INF < dist[7] is false). Uniform trip count per group.
    for (int j = t0 + sub; j < t1; j += SUB) {
      float4 c = c4[j - t0];
      int bv = bs[j - t0];
      float d = fmaxf(fmaf(-2.0f, fmaf(qx, c.x, fmaf(qy, c.y, qz * c.z)), n2 + c.w), 0.0f);
      d = (bv == mybatch) ? d : INFINITY;
      // Branchless sorted insert, strict < (ascending j => per-lane ties keep
      // the earlier index, matching jax.lax.top_k).
      bool lt[KNN];
#pragma unroll
      for (int k = 0; k < KNN; ++k) lt[k] = d < dist[k];
#pragma unroll
      for (int k = KNN - 1; k > 0; --k) {
        dist[k] = lt[k - 1] ? dist[k - 1] : (lt[k] ? d : dist[k]);
        nidx[k] = lt[k - 1] ? nidx[k - 1] : (lt[k] ? j : nidx[k]);
      }
      dist[0] = lt[0] ? d : dist[0];
      nidx[0] = lt[0] ? j : nidx[0];
    }
  }

  // Exact 16-way pop-merge: round r extracts the lexicographic (d, idx) min
  // across the 16-lane group (butterfly => converged in every lane).
#pragma unroll
  for (int r = 0; r < KNN; ++r) {
    float hd = dist[0]; int hx = nidx[0];
    float bd = hd; int bi = hx;
#pragma unroll
    for (int m = 1; m <= 8; m <<= 1) {
      float od = __shfl_xor(bd, m); int oi = __shfl_xor(bi, m);
      if (od < bd || (od == bd && oi < bi)) { bd = od; bi = oi; }
    }
    if (hd == bd && hx == bi) {   // pop winner; (inf,0) pads multi-pop harmlessly
#pragma unroll
      for (int k = 0; k < KNN - 1; ++k) { dist[k] = dist[k + 1]; nidx[k] = nidx[k + 1]; }
      dist[KNN - 1] = INFINITY; nidx[KNN - 1] = 0;
    }
    if (sub == r)
      nbrs[qi][r] = make_float2(bd, __int_as_float(bi));
  }
  __syncthreads();

  // Gather + MSE: wave wv owns queries q0+4*wv..+3; neighbor lists via
  // broadcast ds_read_b128; lane l owns dims l and l+64.
  float pacc = 0.0f;
#pragma unroll
  for (int qq = 0; qq < QPB / (BLK / 64); ++qq) {
    const int lq = wv * (QPB / (BLK / 64)) + qq;
    const int gq = q0 + lq;
    if (gq < N) {                      // wave-uniform
      const float4* pn = (const float4*)&nbrs[lq][0];
      float4 n01 = pn[0], n23 = pn[1], n45 = pn[2], n67 = pn[3];
      float dd[KNN] = {n01.x, n01.z, n23.x, n23.z, n45.x, n45.z, n67.x, n67.z};
      int   id[KNN] = {__float_as_int(n01.y), __float_as_int(n01.w),
                       __float_as_int(n23.y), __float_as_int(n23.w),
                       __float_as_int(n45.y), __float_as_int(n45.w),
                       __float_as_int(n67.y), __float_as_int(n67.w)};
      float w[KNN]; float sw = 0.0f;
#pragma unroll
      for (int r = 0; r < KNN; ++r) { w[r] = 1.0f / fmaxf(dd[r], 1e-16f); sw += w[r]; }
      float acc0 = 0.0f, acc1 = 0.0f;
#pragma unroll
      for (int r = 0; r < KNN; ++r) {
        const float* f = x1 + (size_t)id[r] * ROW + 3;
        acc0 = fmaf(w[r], f[lane], acc0);
        acc1 = fmaf(w[r], f[lane + 64], acc1);
      }
      const float* f2 = x2 + (size_t)gq * ROW + 3;
      float rinv = 1.0f / sw;
      float e0 = fmaf(acc0, rinv, -f2[lane]);
      float e1 = fmaf(acc1, rinv, -f2[lane + 64]);
      pacc += e0 * e0 + e1 * e1;
    }
  }
#pragma unroll
  for (int off = 32; off > 0; off >>= 1) pacc += __shfl_xor(pacc, off);
  if (lane == 0) wred[wv] = pacc;
  __syncthreads();

  // Publish {TAG(bid) | partial} as one 64-bit coherent relaxed store.
  if (tid == 0) {
    float s = 0.0f;
#pragma unroll
    for (int w = 0; w < BLK / 64; ++w) s += wred[w];
    unsigned long long v =
        ((unsigned long long)(0x5A000000u | (unsigned)bid) << 32) |
        (unsigned long long)__float_as_uint(s);
    __hip_atomic_store(&slot[bid], v, __ATOMIC_RELAXED,
                       __HIP_MEMORY_SCOPE_AGENT);
  }

  // Work-block 0 / wave 0: spin-read all slots (deterministic values => any
  // interleaving is bit-identical), fixed-order sum, write result.
  if (bid == 0 && wv == 0) {
    const int nblk = nwg;
    float s = 0.0f;
    for (int r = 0; r * 64 + lane < nblk; ++r) {
      int i = r * 64 + lane;
      unsigned tag = 0x5A000000u | (unsigned)i;
      unsigned long long x = __hip_atomic_load(&slot[i], __ATOMIC_RELAXED,
                                               __HIP_MEMORY_SCOPE_AGENT);
      while ((unsigned)(x >> 32) != tag) {
        __builtin_amdgcn_s_sleep(8);
        x = __hip_atomic_load(&slot[i], __ATOMIC_RELAXED,
                              __HIP_MEMORY_SCOPE_AGENT);
      }
      s += __uint_as_float((unsigned)x);   // lane-local, fixed r-order
    }
#pragma unroll
    for (int off = 32; off > 0; off >>= 1) s += __shfl_xor(s, off);
    if (lane == 0) out[0] = s * scale;
  }
}

extern "C" void kernel_launch(void* const* d_in, const int* in_sizes, int n_in,
                              void* d_out, int out_size, void* d_ws, size_t ws_size,
                              hipStream_t stream) {
  const float* x1 = (const float*)d_in[0];
  const float* x2 = (const float*)d_in[1];
  const int* b1 = (const int*)d_in[2];
  const int* b2 = (const int*)d_in[3];
  int N = in_sizes[2];            // 16384
  int ROW = in_sizes[0] / N;      // 131
  float* out = (float*)d_out;

  int blocks = (N + QPB - 1) / QPB;              // 512
  unsigned long long* slot = (unsigned long long*)d_ws;
  if (ws_size < (size_t)blocks * sizeof(unsigned long long)) return;

  float scale = 1.0f / ((float)N * (float)(ROW - 3));
  knn_one<<<blocks, BLK, 0, stream>>>(x1, x2, b1, b2, N, ROW, scale, slot, out);
}

// Round 13
// 24.641 us; speedup vs baseline: 1.6641x; 1.1081x over previous
//
#include <hip/hip_runtime.h>
#include <math.h>

#define KNN 8
#define QPB 32          // queries per block
#define SUB 16          // sub-lanes per query
#define BLK 512         // QPB*SUB threads, 8 waves
#define CAP 1024        // staged candidates per LDS tile

// Single fused kernel, single dispatch, XCD-swizzled (R12 skeleton).
// R13 deltas: (1) all x2 reads (coords + the 8 feature dims this lane owns)
// hoisted to kernel start -> ~11 independent loads in flight from t=0,
// overlapping search/stage/scan; (2) the feature gather is fused into the
// merge: each popped winner's row loads issue immediately, so all 8 rounds'
// misses pipeline instead of 4 serialized wave-gather rounds.
__launch_bounds__(BLK, 4)
__global__ void knn_one(const float* __restrict__ x1,
                        const float* __restrict__ x2,
                        const int* __restrict__ b1,
                        const int* __restrict__ b2,
                        int N, int ROW, float scale,
                        unsigned long long* __restrict__ slot,
                        float* __restrict__ out) {
  __shared__ float4 c4[CAP];          // {x, y, z, |c|^2}
  __shared__ int   bs[CAP];           // batch id per staged row
  __shared__ int   s_info[2];         // block staging range {s1, e1}
  __shared__ float wred[BLK / 64];

  // Bijective XCD swizzle: consecutive work-ids (same batch) share an XCD L2.
  const int nwg = (int)gridDim.x;
  const int xcd = (int)blockIdx.x & 7, pos = (int)blockIdx.x >> 3;
  const int q8 = nwg >> 3, r8 = nwg & 7;
  const int bid = (xcd < r8) ? xcd * (q8 + 1) + pos
                             : r8 * (q8 + 1) + (xcd - r8) * q8 + pos;

  const int tid  = threadIdx.x;
  const int lane = tid & 63;
  const int wv   = tid >> 6;          // 0..7
  const int qi   = tid >> 4;          // 0..31 query within block
  const int sub  = tid & (SUB - 1);   // lane within 16-group; owned dim base
  const int q0   = bid * QPB;
  const int q    = min(q0 + qi, N - 1);
  const int qlast = min(q0 + QPB - 1, N - 1);

  // Hoisted x2 reads: query coords + this lane's 8 owned feature dims
  // (f2v consumed only in the epilogue -> pure prefetch overlap).
  float qx, qy, qz; int mybatch;
  float f2v[KNN];
  {
    const float* c2 = x2 + (size_t)q * ROW;
    qx = c2[0]; qy = c2[1]; qz = c2[2];
    mybatch = b2[q];
    const float* f2 = c2 + 3 + sub;
#pragma unroll
    for (int t = 0; t < KNN; ++t) f2v[t] = f2[16 * t];
  }
  const float n2 = qx * qx + qy * qy + qz * qz;

  // Wave-cooperative lower_bound on b1 (64-way fanout). Invariant: lb in [lo,hi].
  if (wv < 2) {
    const int bb = (wv == 0) ? b2[q0] : b2[qlast];
    const int target = bb + wv;       // wv0: lb(b_first), wv1: lb(b_last+1)
    int lo = 0, hi = N;
    while (lo < hi) {
      int step = (hi - lo + 63) >> 6;
      int p = lo + lane * step;
      bool pred = (p < hi) && (b1[p] < target);
      int c = __popcll(__ballot(pred));
      if (c == 0) { hi = lo; break; }
      int nlo = lo + (c - 1) * step + 1;
      hi = min(hi, lo + c * step);
      lo = nlo;
    }
    if (lane == 0) s_info[wv] = lo;
  }

  float dist[KNN]; int nidx[KNN];
#pragma unroll
  for (int k = 0; k < KNN; ++k) { dist[k] = INFINITY; nidx[k] = 0; }

  __syncthreads();
  const int s1v = s_info[0], e1v = s_info[1];

  for (int t0 = s1v; t0 < e1v; t0 += CAP) {
    const int t1 = min(t0 + CAP, e1v);
    __syncthreads();                   // c4/bs reuse guard (uniform trip count)
    for (int i = t0 + tid; i < t1; i += BLK) {
      const float* p = x1 + (size_t)i * ROW;
      float cx = p[0], cy = p[1], cz = p[2];
      c4[i - t0] = make_float4(cx, cy, cz, cx * cx + cy * cy + cz * cz);
      bs[i - t0] = b1[i];
    }
    __syncthreads();
    // All lanes scan the whole tile; foreign-batch rows masked to INF.
    for (int j = t0 + sub; j < t1; j += SUB) {
      float4 c = c4[j - t0];
      int bv = bs[j - t0];
      float d = fmaxf(fmaf(-2.0f, fmaf(qx, c.x, fmaf(qy, c.y, qz * c.z)), n2 + c.w), 0.0f);
      d = (bv == mybatch) ? d : INFINITY;
      // Branchless sorted insert, strict < (ascending j => per-lane ties keep
      // the earlier index, matching jax.lax.top_k).
      bool lt[KNN];
#pragma unroll
      for (int k = 0; k < KNN; ++k) lt[k] = d < dist[k];
#pragma unroll
      for (int k = KNN - 1; k > 0; --k) {
        dist[k] = lt[k - 1] ? dist[k - 1] : (lt[k] ? d : dist[k]);
        nidx[k] = lt[k - 1] ? nidx[k - 1] : (lt[k] ? j : nidx[k]);
      }
      dist[0] = lt[0] ? d : dist[0];
      nidx[0] = lt[0] ? j : nidx[0];
    }
  }

  // Fused exact merge + gather. Round r: lexicographic (d, idx) min across
  // the 16-lane group (butterfly => converged in every lane); pop the owner;
  // every lane immediately issues that row's loads for its 8 owned dims.
  // Rounds' loads pipeline (next round's shfls don't depend on them).
  // Padded (inf,0) entries: w=0, row 0 loaded harmlessly, acc += 0.
  float acc[KNN];
#pragma unroll
  for (int t = 0; t < KNN; ++t) acc[t] = 0.f;
  float sw = 0.f;
  const float* x1f = x1 + 3 + sub;
#pragma unroll
  for (int r = 0; r < KNN; ++r) {
    float hd = dist[0]; int hx = nidx[0];
    float bd = hd; int bi = hx;
#pragma unroll
    for (int m = 1; m <= 8; m <<= 1) {
      float od = __shfl_xor(bd, m); int oi = __shfl_xor(bi, m);
      if (od < bd || (od == bd && oi < bi)) { bd = od; bi = oi; }
    }
    if (hd == bd && hx == bi) {   // pop winner; (inf,0) pads multi-pop harmlessly
#pragma unroll
      for (int k = 0; k < KNN - 1; ++k) { dist[k] = dist[k + 1]; nidx[k] = nidx[k + 1]; }
      dist[KNN - 1] = INFINITY; nidx[KNN - 1] = 0;
    }
    float w = 1.0f / fmaxf(bd, 1e-16f);   // d=inf (pad) -> w = 0
    sw += w;
    const float* f = x1f + (size_t)bi * ROW;
#pragma unroll
    for (int t = 0; t < KNN; ++t) acc[t] = fmaf(w, f[16 * t], acc[t]);
  }

  // Epilogue: this lane's 8 dims of its query's squared error.
  float pacc = 0.0f;
  if (q0 + qi < N) {
    float rinv = 1.0f / sw;
#pragma unroll
    for (int t = 0; t < KNN; ++t) {
      float e = fmaf(acc[t], rinv, -f2v[t]);
      pacc += e * e;
    }
  }
  // Wave sum: the 4 groups of a wave hold disjoint dims of 4 queries.
#pragma unroll
  for (int off = 32; off > 0; off >>= 1) pacc += __shfl_xor(pacc, off);
  if (lane == 0) wred[wv] = pacc;
  __syncthreads();

  // Publish {TAG(bid) | partial} as one 64-bit agent-scope relaxed store.
  if (tid == 0) {
    float s = 0.0f;
#pragma unroll
    for (int w = 0; w < BLK / 64; ++w) s += wred[w];
    unsigned long long v =
        ((unsigned long long)(0x5A000000u | (unsigned)bid) << 32) |
        (unsigned long long)__float_as_uint(s);
    __hip_atomic_store(&slot[bid], v, __ATOMIC_RELAXED,
                       __HIP_MEMORY_SCOPE_AGENT);
  }

  // Work-block 0 / wave 0: spin-read all slots (deterministic values => any
  // interleaving is bit-identical), fixed-order sum, write result.
  if (bid == 0 && wv == 0) {
    const int nblk = nwg;
    float s = 0.0f;
    for (int r = 0; r * 64 + lane < nblk; ++r) {
      int i = r * 64 + lane;
      unsigned tag = 0x5A000000u | (unsigned)i;
      unsigned long long x = __hip_atomic_load(&slot[i], __ATOMIC_RELAXED,
                                               __HIP_MEMORY_SCOPE_AGENT);
      while ((unsigned)(x >> 32) != tag) {
        __builtin_amdgcn_s_sleep(8);
        x = __hip_atomic_load(&slot[i], __ATOMIC_RELAXED,
                              __HIP_MEMORY_SCOPE_AGENT);
      }
      s += __uint_as_float((unsigned)x);   // lane-local, fixed r-order
    }
#pragma unroll
    for (int off = 32; off > 0; off >>= 1) s += __shfl_xor(s, off);
    if (lane == 0) out[0] = s * scale;
  }
}

extern "C" void kernel_launch(void* const* d_in, const int* in_sizes, int n_in,
                              void* d_out, int out_size, void* d_ws, size_t ws_size,
                              hipStream_t stream) {
  const float* x1 = (const float*)d_in[0];
  const float* x2 = (const float*)d_in[1];
  const int* b1 = (const int*)d_in[2];
  const int* b2 = (const int*)d_in[3];
  int N = in_sizes[2];            // 16384
  int ROW = in_sizes[0] / N;      // 131
  float* out = (float*)d_out;

  int blocks = (N + QPB - 1) / QPB;              // 512
  unsigned long long* slot = (unsigned long long*)d_ws;
  if (ws_size < (size_t)blocks * sizeof(unsigned long long)) return;

  float scale = 1.0f / ((float)N * (float)(ROW - 3));
  knn_one<<<blocks, BLK, 0, stream>>>(x1, x2, b1, b2, N, ROW, scale, slot, out);
}